// Round 1
// baseline (944.935 us; speedup 1.0000x reference)
//
#include <hip/hip_runtime.h>
#include <cstdint>
#include <cstddef>

// Problem constants (B=1, S=65536, D=1024, P=512, E=3, C=2)
#define T_TOK 65536
#define DDIM  1024
#define PDIM  512

typedef __attribute__((ext_vector_type(8))) short          shortx8;
typedef __attribute__((ext_vector_type(8))) unsigned short ushortx8;
typedef __attribute__((ext_vector_type(4))) float          floatx4;

__device__ __forceinline__ unsigned short f2bf_rn(float x){
  unsigned int u = __float_as_uint(x);
  unsigned int r = u + 0x7FFFu + ((u >> 16) & 1u);
  return (unsigned short)(r >> 16);
}
__device__ __forceinline__ float bf2f(unsigned short h){
  return __uint_as_float(((unsigned int)h) << 16);
}

// ---------------------------------------------------------------------------
// prep: zero hist/params, build transposed split-bf16 copies of W_t1 and W_a1
//   W1t[p][k] = W_t1[k][p]  (P=512 rows, K=1024)
//   Wat[n][k] = W_a1[k][n]  (512 rows, K=512)
// ---------------------------------------------------------------------------
__global__ void prep(const float* __restrict__ Wt1, const float* __restrict__ Wa1,
                     unsigned short* __restrict__ W1th, unsigned short* __restrict__ W1tl,
                     unsigned short* __restrict__ Wath, unsigned short* __restrict__ Watl,
                     int* __restrict__ hist, int* __restrict__ params)
{
  int gid = blockIdx.x * 256 + threadIdx.x;
  if (gid < 196608){ hist[gid] = 0; return; }
  if (gid < 196672){ params[gid - 196608] = 0; return; }
  int i = gid - 196672;
  if (i < 524288){
    int p = i >> 10, k = i & 1023;
    float x = Wt1[(size_t)k * PDIM + p];
    unsigned short h = f2bf_rn(x);
    W1th[i] = h;
    W1tl[i] = f2bf_rn(x - bf2f(h));
    return;
  }
  int i2 = i - 524288;
  if (i2 < 262144){
    int n = i2 >> 9, k = i2 & 511;
    float x = Wa1[(size_t)k * PDIM + n];
    unsigned short h = f2bf_rn(x);
    Wath[i2] = h;
    Watl[i2] = f2bf_rn(x - bf2f(h));
  }
}

// ---------------------------------------------------------------------------
// Split-bf16 GEMM: C = tanh(A(fp32) @ B), B pre-split into hi/lo bf16,
// A converted to hi/lo on the fly. 3 MFMA products => ~fp32 accuracy.
// 128x128 tile, BK=32, 256 threads (4 waves, each 64x64 = 4x4 MFMA tiles).
// MODE 0: store C (patches) + unweighted column sums -> colpart (for bag)
// MODE 1: no store; weight rows by total_sel and column-sum -> colpart (agg)
// ---------------------------------------------------------------------------
template<int MODE>
__global__ __launch_bounds__(256, 2)
void gemm_split(const float* __restrict__ A,
                const unsigned short* __restrict__ Bhg,
                const unsigned short* __restrict__ Blg,
                int K,
                float* __restrict__ Cout,
                float* __restrict__ colpart,
                const unsigned char* __restrict__ s0,
                const unsigned char* __restrict__ s1,
                const unsigned char* __restrict__ s2)
{
  __shared__ unsigned short Ah[128][40];  // +8 pad: stride 80B = 20 banks, conflict-free-ish
  __shared__ unsigned short Al[128][40];
  __shared__ unsigned short Bh[128][40];
  __shared__ unsigned short Bl[128][40];
  __shared__ float colsum[128];
  __shared__ float tsel[128];

  const int tid = threadIdx.x;
  const int m0 = blockIdx.y * 128;
  const int n0 = blockIdx.x * 128;

  if (MODE == 1 && tid < 128){
    int t = m0 + tid;
    tsel[tid] = (float)(s0[t] + s1[t] + s2[t]);
  }

  const int lane = tid & 63;
  const int wv   = tid >> 6;
  const int wm   = (wv & 1) << 6;
  const int wn   = (wv >> 1) << 6;
  const int lr   = lane & 15;
  const int quad = lane >> 4;
  const int kb8  = quad << 3;

  floatx4 acc[4][4];
  #pragma unroll
  for (int i = 0; i < 4; i++)
    #pragma unroll
    for (int j = 0; j < 4; j++)
      acc[i][j] = (floatx4){0.f, 0.f, 0.f, 0.f};

  const int nkb = K >> 5;
  for (int kb = 0; kb < nkb; ++kb){
    const int k0 = kb << 5;
    // stage A (fp32 -> hi/lo bf16)
    #pragma unroll
    for (int i = 0; i < 4; i++){
      int lin = i * 256 + tid;
      int row = lin >> 3;
      int kq  = (lin & 7) << 2;
      const float4 v = *(const float4*)(A + (size_t)(m0 + row) * K + k0 + kq);
      ushort4 h, l;
      h.x = f2bf_rn(v.x); l.x = f2bf_rn(v.x - bf2f(h.x));
      h.y = f2bf_rn(v.y); l.y = f2bf_rn(v.y - bf2f(h.y));
      h.z = f2bf_rn(v.z); l.z = f2bf_rn(v.z - bf2f(h.z));
      h.w = f2bf_rn(v.w); l.w = f2bf_rn(v.w - bf2f(h.w));
      *(ushort4*)&Ah[row][kq] = h;
      *(ushort4*)&Al[row][kq] = l;
    }
    // stage B (already split bf16, [n][k] layout)
    #pragma unroll
    for (int i = 0; i < 2; i++){
      int lin = i * 256 + tid;
      int row = lin >> 2;
      int kq  = (lin & 3) << 3;
      size_t off = (size_t)(n0 + row) * K + k0 + kq;
      *(ushortx8*)&Bh[row][kq] = *(const ushortx8*)(Bhg + off);
      *(ushortx8*)&Bl[row][kq] = *(const ushortx8*)(Blg + off);
    }
    __syncthreads();
    shortx8 a0[4], a1[4], b0[4], b1[4];
    #pragma unroll
    for (int i = 0; i < 4; i++){
      a0[i] = *(const shortx8*)&Ah[wm + i * 16 + lr][kb8];
      a1[i] = *(const shortx8*)&Al[wm + i * 16 + lr][kb8];
      b0[i] = *(const shortx8*)&Bh[wn + i * 16 + lr][kb8];
      b1[i] = *(const shortx8*)&Bl[wn + i * 16 + lr][kb8];
    }
    #pragma unroll
    for (int i = 0; i < 4; i++){
      #pragma unroll
      for (int j = 0; j < 4; j++){
        acc[i][j] = __builtin_amdgcn_mfma_f32_16x16x32_bf16(a0[i], b0[j], acc[i][j], 0, 0, 0);
        acc[i][j] = __builtin_amdgcn_mfma_f32_16x16x32_bf16(a1[i], b0[j], acc[i][j], 0, 0, 0);
        acc[i][j] = __builtin_amdgcn_mfma_f32_16x16x32_bf16(a0[i], b1[j], acc[i][j], 0, 0, 0);
      }
    }
    __syncthreads();
  }

  // epilogue: tanh (+store / +weight) and column partial sums
  float csum[4] = {0.f, 0.f, 0.f, 0.f};
  #pragma unroll
  for (int i = 0; i < 4; i++){
    float w0 = 1.f, w1 = 1.f, w2 = 1.f, w3 = 1.f;
    if (MODE == 1){
      const float4 wv4 = *(const float4*)&tsel[wm + i * 16 + (quad << 2)];
      w0 = wv4.x; w1 = wv4.y; w2 = wv4.z; w3 = wv4.w;
    }
    #pragma unroll
    for (int j = 0; j < 4; j++){
      float t0 = tanhf(acc[i][j][0]);
      float t1 = tanhf(acc[i][j][1]);
      float t2 = tanhf(acc[i][j][2]);
      float t3 = tanhf(acc[i][j][3]);
      if (MODE == 0){
        size_t base = (size_t)(m0 + wm + i * 16 + (quad << 2)) * PDIM + (n0 + wn + j * 16 + lr);
        Cout[base]            = t0;
        Cout[base +     PDIM] = t1;
        Cout[base + 2 * PDIM] = t2;
        Cout[base + 3 * PDIM] = t3;
        csum[j] += t0 + t1 + t2 + t3;
      } else {
        csum[j] += t0 * w0 + t1 * w1 + t2 * w2 + t3 * w3;
      }
    }
  }
  #pragma unroll
  for (int j = 0; j < 4; j++){
    float s = csum[j];
    s += __shfl_xor(s, 16);
    s += __shfl_xor(s, 32);
    csum[j] = s;
  }
  __syncthreads();
  if (tid < 128) colsum[tid] = 0.f;
  __syncthreads();
  if (lane < 16){
    #pragma unroll
    for (int j = 0; j < 4; j++) atomicAdd(&colsum[wn + j * 16 + lane], csum[j]);
  }
  __syncthreads();
  if (tid < 128) colpart[(size_t)blockIdx.y * PDIM + blockIdx.x * 128 + tid] = colsum[tid];
}

// ---------------------------------------------------------------------------
// gates: per token, 3 gate GEMVs (fp32), router_logits out, w_top0 key (uint),
// masks, per-expert counts, and level-1 (16-bit) key histograms.
// One wave per token (grid-stride).
// ---------------------------------------------------------------------------
__global__ void gates_kernel(const float* __restrict__ patches,
                             const float* __restrict__ Wg0,
                             const float* __restrict__ Wg1,
                             const float* __restrict__ Wg2,
                             float* __restrict__ dout,
                             unsigned int* __restrict__ wkey,
                             unsigned char* __restrict__ mask3,
                             int* __restrict__ params,
                             int* __restrict__ hist)
{
  __shared__ int lc[3];
  const int tid = threadIdx.x;
  if (tid < 3) lc[tid] = 0;
  __syncthreads();
  const int lane = tid & 63;
  float wg[3][16];
  const float* Wgp[3] = {Wg0, Wg1, Wg2};
  #pragma unroll
  for (int g = 0; g < 3; g++){
    #pragma unroll
    for (int j = 0; j < 4; j++){
      float4 v = *(const float4*)(Wgp[g] + lane * 16 + j * 4);
      wg[g][j * 4 + 0] = v.x; wg[g][j * 4 + 1] = v.y;
      wg[g][j * 4 + 2] = v.z; wg[g][j * 4 + 3] = v.w;
    }
  }
  const int nw = gridDim.x << 2;
  for (int t = blockIdx.x * 4 + (tid >> 6); t < T_TOK; t += nw){
    const float* row = patches + (size_t)t * PDIM + lane * 8;
    float4 v0 = *(const float4*)row;
    float4 v1 = *(const float4*)(row + 4);
    float x[8] = {v0.x, v0.y, v0.z, v0.w, v1.x, v1.y, v1.z, v1.w};
    float g00 = 0, g01 = 0, g10 = 0, g11 = 0, g20 = 0, g21 = 0;
    #pragma unroll
    for (int j = 0; j < 8; j++){
      g00 += x[j] * wg[0][2 * j]; g01 += x[j] * wg[0][2 * j + 1];
      g10 += x[j] * wg[1][2 * j]; g11 += x[j] * wg[1][2 * j + 1];
      g20 += x[j] * wg[2][2 * j]; g21 += x[j] * wg[2][2 * j + 1];
    }
    #pragma unroll
    for (int off = 1; off < 64; off <<= 1){
      g00 += __shfl_xor(g00, off); g01 += __shfl_xor(g01, off);
      g10 += __shfl_xor(g10, off); g11 += __shfl_xor(g11, off);
      g20 += __shfl_xor(g20, off); g21 += __shfl_xor(g21, off);
    }
    if (lane == 0){
      dout[8 + 2 * t]     = g00;   // router_logits output
      dout[8 + 2 * t + 1] = g01;
      int m0 = g01 > g00;
      int m1 = g11 > g10;
      int m2 = g21 > g20;
      mask3[t] = (unsigned char)(m0 | (m1 << 1) | (m2 << 2));
      float d = fabsf(g00 - g01);
      float w = 1.0f / (1.0f + expf(-d));   // top-1 softmax prob in [0.5,1)
      unsigned int u = __float_as_uint(w);
      u = u < 0x3F000000u ? 0x3F000000u : u;
      u = u > 0x3F7FFFFFu ? 0x3F7FFFFFu : u;
      wkey[t] = u;
      int b = (int)((u >> 7) - 0x7E0000u);  // mantissa bits [22:7]
      if (m0){ atomicAdd(&hist[b], 1);          atomicAdd(&lc[0], 1); }
      if (m1){ atomicAdd(&hist[65536 + b], 1);  atomicAdd(&lc[1], 1); }
      if (m2){ atomicAdd(&hist[131072 + b], 1); atomicAdd(&lc[2], 1); }
    }
  }
  __syncthreads();
  if (tid < 3 && lc[tid]) atomicAdd(&params[tid], lc[tid]);
}

// ---------------------------------------------------------------------------
// find_bucket: per expert, nums = floor(cnt*frac) (exact as shifts), then
// locate the 16-bit bucket containing the nums-th largest key (suffix scans).
// params: [0..2]=cnt [3..5]=nums [6..8]=bucket [9..11]=rank_in_bucket
//         [12..14]=theta_u [15..17]=r_ties [18..20]=c_eq
// ---------------------------------------------------------------------------
__global__ void find_bucket(int* __restrict__ params, const int* __restrict__ hist)
{
  __shared__ int cs[256];
  __shared__ int orig[256];
  __shared__ int selc;
  __shared__ int selrk;
  const int tid = threadIdx.x;
  for (int e = 0; e < 3; e++){
    int cnt = params[e];
    int shift = (e == 1) ? 1 : 2;           // FRACS = 0.25, 0.5, 0.25 (exact)
    int nums = cnt >> shift;
    if (nums == 0) nums = cnt;
    if (tid == 0) params[3 + e] = nums;
    __syncthreads();
    if (nums == 0){
      if (tid == 0){ params[6 + e] = -1; params[9 + e] = 0; }
      __syncthreads();
      continue;
    }
    int s = 0;
    const int* h = hist + e * 65536 + tid * 256;
    for (int j = 0; j < 256; j++) s += h[j];
    cs[tid] = s; orig[tid] = s;
    __syncthreads();
    for (int off = 1; off < 256; off <<= 1){
      int v = (tid + off < 256) ? cs[tid + off] : 0;
      __syncthreads();
      cs[tid] += v;
      __syncthreads();
    }
    if (cs[tid] >= nums && (cs[tid] - orig[tid]) < nums){
      selc = tid; selrk = nums - (cs[tid] - orig[tid]);
    }
    __syncthreads();
    int ch = selc, rk = selrk;
    int hb = hist[e * 65536 + ch * 256 + tid];
    cs[tid] = hb; orig[tid] = hb;
    __syncthreads();
    for (int off = 1; off < 256; off <<= 1){
      int v = (tid + off < 256) ? cs[tid + off] : 0;
      __syncthreads();
      cs[tid] += v;
      __syncthreads();
    }
    if (cs[tid] >= rk && (cs[tid] - orig[tid]) < rk){
      params[6 + e] = ch * 256 + tid;
      params[9 + e] = rk - (cs[tid] - orig[tid]);
    }
    __syncthreads();
  }
}

// ---------------------------------------------------------------------------
// level2: within the chosen bucket, 128-bin histogram over mantissa bits
// [6:0] gives the exact threshold key theta_u, ties-to-take r, tie count c_eq.
// ---------------------------------------------------------------------------
__global__ void level2(int* __restrict__ params, const unsigned int* __restrict__ wkey,
                       const unsigned char* __restrict__ mask3)
{
  const int e = blockIdx.x;
  const int tid = threadIdx.x;
  __shared__ int h2[128];
  __shared__ int o2[128];
  int B = params[6 + e];
  int rank = params[9 + e];
  if (B < 0){
    if (tid == 0){ params[12 + e] = (int)0xFFFFFFFFu; params[15 + e] = 0; params[18 + e] = 0; }
    return;
  }
  if (tid < 128) h2[tid] = 0;
  __syncthreads();
  const unsigned char bit = (unsigned char)(1u << e);
  for (int t = tid; t < T_TOK; t += 256){
    if (mask3[t] & bit){
      unsigned int u = wkey[t];
      if ((int)((u >> 7) - 0x7E0000u) == B) atomicAdd(&h2[u & 127u], 1);
    }
  }
  __syncthreads();
  if (tid < 128) o2[tid] = h2[tid];
  __syncthreads();
  for (int off = 1; off < 128; off <<= 1){
    int v = 0;
    if (tid < 128 && tid + off < 128) v = h2[tid + off];
    __syncthreads();
    if (tid < 128) h2[tid] += v;
    __syncthreads();
  }
  if (tid < 128 && h2[tid] >= rank && (h2[tid] - o2[tid]) < rank){
    params[12 + e] = (int)((((unsigned)B + 0x7E0000u) << 7) | (unsigned)tid);
    params[15 + e] = rank - (h2[tid] - o2[tid]);
    params[18 + e] = o2[tid];
  }
}

// ---------------------------------------------------------------------------
// mark_sel: sel[t] = mask & (key > theta || (key == theta && idx-rank < r)).
// Fast path (c_eq == r, the overwhelmingly common case): pure parallel.
// Slow path: single block, stable index-ordered scan over ties.
// ---------------------------------------------------------------------------
__global__ void mark_sel(const int* __restrict__ params, const unsigned int* __restrict__ wkey,
                         const unsigned char* __restrict__ mask3, unsigned char* __restrict__ selb)
{
  const int e = blockIdx.y;
  const int bx = blockIdx.x;
  const int tid = threadIdx.x;
  const unsigned int theta = (unsigned int)params[12 + e];
  const int r = params[15 + e];
  const int ceq = params[18 + e];
  const unsigned char bit = (unsigned char)(1u << e);
  unsigned char* sb = selb + e * T_TOK;
  if (ceq == r){
    int t0 = bx * 2048;
    #pragma unroll
    for (int i = 0; i < 8; i++){
      int t = t0 + i * 256 + tid;
      unsigned char mk = mask3[t] & bit;
      sb[t] = (mk && wkey[t] >= theta) ? 1 : 0;
    }
  } else {
    if (bx) return;
    __shared__ int basec;
    __shared__ int wsum[4];
    if (tid == 0) basec = 0;
    __syncthreads();
    const int lane = tid & 63, w = tid >> 6;
    for (int c = 0; c < 256; c++){
      int t = c * 256 + tid;
      unsigned char mk = mask3[t] & bit;
      unsigned int u = mk ? wkey[t] : 0u;
      bool gt = mk && (u > theta);
      bool eq = mk && (u == theta);
      unsigned long long bal = __ballot(eq);
      if (lane == 0) wsum[w] = __popcll(bal);
      __syncthreads();
      int wbase = 0;
      for (int ww = 0; ww < w; ww++) wbase += wsum[ww];
      int pos = basec + wbase + __popcll(bal & ((1ull << lane) - 1ull));
      sb[t] = (gt || (eq && pos < r)) ? 1 : 0;
      __syncthreads();
      if (tid == 0) basec += wsum[0] + wsum[1] + wsum[2] + wsum[3];
      __syncthreads();
    }
  }
}

// ---------------------------------------------------------------------------
// meanfeat_part: partial column sums of patches over selected tokens,
// experts 0 and 1 only (expert 2's mean_feat is unused by any output).
// ---------------------------------------------------------------------------
__global__ void meanfeat_part(const float* __restrict__ patches,
                              const unsigned char* __restrict__ selb,
                              float* __restrict__ mfpart)
{
  const int bx = blockIdx.x, tid = threadIdx.x;
  __shared__ unsigned char f0s[256], f1s[256];
  const int t0 = bx * 256;
  f0s[tid] = selb[t0 + tid];
  f1s[tid] = selb[T_TOK + t0 + tid];
  __syncthreads();
  float s00 = 0, s01 = 0, s10 = 0, s11 = 0;
  for (int i = 0; i < 256; i++){
    int f0 = f0s[i], f1 = f1s[i];
    if (f0 | f1){
      float2 v = *(const float2*)(patches + (size_t)(t0 + i) * PDIM + tid * 2);
      if (f0){ s00 += v.x; s01 += v.y; }
      if (f1){ s10 += v.x; s11 += v.y; }
    }
  }
  float* o = mfpart + (size_t)bx * 1024;
  o[tid * 2] = s00; o[tid * 2 + 1] = s01;
  o[512 + tid * 2] = s10; o[512 + tid * 2 + 1] = s11;
}

// ---------------------------------------------------------------------------
// reduce_parts: bagsum[512] | aggsum[512] | mfsum[2][512] into outsmall
// ---------------------------------------------------------------------------
__global__ void reduce_parts(const float* __restrict__ bagpart, const float* __restrict__ aggpart,
                             const float* __restrict__ mfpart, float* __restrict__ outsmall)
{
  int gid = blockIdx.x * 256 + threadIdx.x;  // 0..2047
  float s = 0.f;
  if (gid < 512){
    for (int mb = 0; mb < 512; mb++) s += bagpart[(size_t)mb * 512 + gid];
    outsmall[gid] = s;
  } else if (gid < 1024){
    int p = gid - 512;
    for (int mb = 0; mb < 512; mb++) s += aggpart[(size_t)mb * 512 + p];
    outsmall[512 + p] = s;
  } else {
    int idx = gid - 1024;
    int e = idx >> 9, p = idx & 511;
    for (int b = 0; b < 256; b++) s += mfpart[(size_t)b * 1024 + e * 512 + p];
    outsmall[1024 + idx] = s;
  }
}

// ---------------------------------------------------------------------------
// finalize: all small outputs.
// d_out layout: [0,2) e_Y_logits | [2] e_Y_hat | [3,5) Y_logits | [5,7) Y_prob
//   | [7] Y_hat | [8,131080) router_logits | [131080] joint | [131081,131085) distribute
// ---------------------------------------------------------------------------
__global__ void finalize(const float* __restrict__ outsmall, const int* __restrict__ params,
                         const float* __restrict__ Wcls1, const float* __restrict__ Wclf,
                         const float* __restrict__ Wacls, float* __restrict__ dout)
{
  const int lane = threadIdx.x;  // 64 threads
  const int nums0 = params[3], nums1 = params[4], nums2 = params[5];
  const float invT = 1.0f / 65536.0f;
  const float inv0 = 1.0f / (float)(nums0 > 0 ? nums0 : 1);
  const float inv1 = 1.0f / (float)(nums1 > 0 ? nums1 : 1);
  const float totn = (float)(nums0 + nums1 + nums2);
  const float invA = 1.0f / fmaxf(totn, 1.0f);
  float y0 = 0, y1 = 0, a0 = 0, a1 = 0;
  float l00 = 0, l01 = 0, l02 = 0, l10 = 0, l11 = 0, l12 = 0;
  #pragma unroll
  for (int j = 0; j < 8; j++){
    int p = lane * 8 + j;
    float bg = outsmall[p] * invT;
    y0 += bg * Wcls1[p * 2]; y1 += bg * Wcls1[p * 2 + 1];
    float ag = outsmall[512 + p] * invA;
    a0 += ag * Wacls[p * 2]; a1 += ag * Wacls[p * 2 + 1];
    float m0v = outsmall[1024 + p] * inv0;
    l00 += m0v * Wclf[p * 3]; l01 += m0v * Wclf[p * 3 + 1]; l02 += m0v * Wclf[p * 3 + 2];
    float m1v = outsmall[1536 + p] * inv1;
    l10 += m1v * Wclf[1536 + p * 3]; l11 += m1v * Wclf[1536 + p * 3 + 1]; l12 += m1v * Wclf[1536 + p * 3 + 2];
  }
  #pragma unroll
  for (int off = 1; off < 64; off <<= 1){
    y0 += __shfl_xor(y0, off);   y1 += __shfl_xor(y1, off);
    a0 += __shfl_xor(a0, off);   a1 += __shfl_xor(a1, off);
    l00 += __shfl_xor(l00, off); l01 += __shfl_xor(l01, off); l02 += __shfl_xor(l02, off);
    l10 += __shfl_xor(l10, off); l11 += __shfl_xor(l11, off); l12 += __shfl_xor(l12, off);
  }
  if (lane == 0){
    dout[0] = a0; dout[1] = a1;
    dout[2] = (a1 > a0) ? 1.0f : 0.0f;
    dout[3] = y0; dout[4] = y1;
    float mx = fmaxf(y0, y1), e0 = expf(y0 - mx), e1 = expf(y1 - mx), inv = 1.0f / (e0 + e1);
    dout[5] = e0 * inv; dout[6] = e1 * inv;
    dout[7] = (y1 > y0) ? 1.0f : 0.0f;
    float m3 = fmaxf(fmaxf(l00, l01), l02);
    float lse0 = m3 + logf(expf(l00 - m3) + expf(l01 - m3) + expf(l02 - m3));
    float m4 = fmaxf(fmaxf(l10, l11), l12);
    float lse1 = m4 + logf(expf(l10 - m4) + expf(l11 - m4) + expf(l12 - m4));
    dout[131080] = (lse0 - l00) + (lse1 - l11);
    dout[131081] = 65536.0f;
    dout[131082] = (float)nums0;
    dout[131083] = (float)nums1;
    dout[131084] = (float)nums2;
  }
}

// ---------------------------------------------------------------------------
extern "C" void kernel_launch(void* const* d_in, const int* in_sizes, int n_in,
                              void* d_out, int out_size, void* d_ws, size_t ws_size,
                              hipStream_t stream)
{
  const float* X      = (const float*)d_in[0];
  const float* W_t1   = (const float*)d_in[1];
  const float* W_cls1 = (const float*)d_in[2];
  const float* Wg0    = (const float*)d_in[3];
  const float* Wg1    = (const float*)d_in[4];
  const float* Wg2    = (const float*)d_in[5];
  const float* W_clf  = (const float*)d_in[6];
  const float* W_a1   = (const float*)d_in[7];
  const float* W_acls = (const float*)d_in[8];
  float* dout = (float*)d_out;
  char* ws = (char*)d_ws;

  // workspace layout (all offsets 256B-aligned), total ~135.3 MB
  float*          patches  = (float*)         (ws + 0);
  unsigned short* W1th     = (unsigned short*)(ws + 134217728);
  unsigned short* W1tl     = (unsigned short*)(ws + 135266304);
  unsigned short* Wath     = (unsigned short*)(ws + 136314880);
  unsigned short* Watl     = (unsigned short*)(ws + 136839168);
  unsigned int*   wkey     = (unsigned int*)  (ws + 137363456);
  unsigned char*  mask3    = (unsigned char*) (ws + 137625600);
  unsigned char*  selb     = (unsigned char*) (ws + 137691136);
  int*            hist     = (int*)           (ws + 137887744);
  int*            params   = (int*)           (ws + 138674176);
  float*          bagpart  = (float*)         (ws + 138674432);
  float*          aggpart  = (float*)         (ws + 139723008);
  float*          mfpart   = (float*)         (ws + 140771584);
  float*          outsmall = (float*)         (ws + 141820160);

  prep<<<3841, 256, 0, stream>>>(W_t1, W_a1, W1th, W1tl, Wath, Watl, hist, params);

  gemm_split<0><<<dim3(4, 512), 256, 0, stream>>>(
      X, W1th, W1tl, DDIM, patches, bagpart, nullptr, nullptr, nullptr);

  gates_kernel<<<512, 256, 0, stream>>>(
      patches, Wg0, Wg1, Wg2, dout, wkey, mask3, params, hist);

  find_bucket<<<1, 256, 0, stream>>>(params, hist);
  level2<<<3, 256, 0, stream>>>(params, wkey, mask3);
  mark_sel<<<dim3(32, 3), 256, 0, stream>>>(params, wkey, mask3, selb);

  meanfeat_part<<<256, 256, 0, stream>>>(patches, selb, mfpart);

  gemm_split<1><<<dim3(4, 512), 256, 0, stream>>>(
      patches, Wath, Watl, PDIM, nullptr, aggpart,
      selb, selb + T_TOK, selb + 2 * T_TOK);

  reduce_parts<<<8, 256, 0, stream>>>(bagpart, aggpart, mfpart, outsmall);

  finalize<<<1, 64, 0, stream>>>(outsmall, params, W_cls1, W_clf, W_acls, dout);
}

// Round 2
// 716.759 us; speedup vs baseline: 1.3183x; 1.3183x over previous
//
#include <hip/hip_runtime.h>
#include <cstdint>
#include <cstddef>

// Problem constants (B=1, S=65536, D=1024, P=512, E=3, C=2)
#define T_TOK 65536
#define DDIM  1024
#define PDIM  512

typedef __attribute__((ext_vector_type(8))) short          shortx8;
typedef __attribute__((ext_vector_type(8))) unsigned short ushortx8;
typedef __attribute__((ext_vector_type(4))) float          floatx4;

__device__ __forceinline__ unsigned short f2bf_rn(float x){
  unsigned int u = __float_as_uint(x);
  unsigned int r = u + 0x7FFFu + ((u >> 16) & 1u);
  return (unsigned short)(r >> 16);
}
__device__ __forceinline__ float bf2f(unsigned short h){
  return __uint_as_float(((unsigned int)h) << 16);
}
// fast tanh, NaN-safe at +-inf of exp
__device__ __forceinline__ float ftanh(float x){
  float ez = __expf(2.f * x);
  return 1.f - 2.f / (ez + 1.f);
}

// ---------------------------------------------------------------------------
// prep: zero [hist1 3x4096 | h2 3x2048 | params 64 | bagsum 512 | aggsum 512
//             | mf 1024]  (20544 ints), split-transpose W_t1 / W_a1 to bf16
// hi/lo (rounded hi + exact-residual rounded lo).
// ---------------------------------------------------------------------------
__global__ void prep(const float* __restrict__ Wt1, const float* __restrict__ Wa1,
                     unsigned short* __restrict__ W1th, unsigned short* __restrict__ W1tl,
                     unsigned short* __restrict__ Wath, unsigned short* __restrict__ Watl,
                     int* __restrict__ zbase)
{
  int gid = blockIdx.x * 256 + threadIdx.x;
  if (gid < 20544){ zbase[gid] = 0; return; }
  int i = gid - 20544;
  if (i < 524288){
    int p = i >> 10, k = i & 1023;
    float x = Wt1[(size_t)k * PDIM + p];
    unsigned short h = f2bf_rn(x);
    W1th[i] = h;
    W1tl[i] = f2bf_rn(x - bf2f(h));
    return;
  }
  i -= 524288;
  if (i < 262144){
    int n = i >> 9, k = i & 511;
    float x = Wa1[(size_t)k * PDIM + n];
    unsigned short h = f2bf_rn(x);
    Wath[i] = h;
    Watl[i] = f2bf_rn(x - bf2f(h));
  }
}

// ---------------------------------------------------------------------------
// Split-bf16 GEMM: C = tanh(A(fp32) @ B). B pre-split hi/lo; A split on the
// fly by truncation (hi = top16 bits, lo = top16 of exact residual).
// 128x128 tile, BK=32, 256 threads (4 waves of 64x64 = 4x4 MFMA tiles).
// MODE 0: store C (patches); unweighted column sums -> atomicAdd colacc (bag)
// MODE 1: rows indirected through cidx (compacted union), weighted by wgt;
//         no C store; weighted column sums -> atomicAdd colacc (agg)
// ---------------------------------------------------------------------------
template<int MODE>
__global__ __launch_bounds__(256, 2)
void gemm_split(const float* __restrict__ A,
                const unsigned short* __restrict__ Bhg,
                const unsigned short* __restrict__ Blg,
                float* __restrict__ Cout,
                float* __restrict__ colacc,
                const int* __restrict__ cidx,
                const float* __restrict__ wgt,
                const int* __restrict__ params)
{
  constexpr int K = (MODE == 0) ? 1024 : 512;
  __shared__ unsigned short Ah[128][40];   // stride 80B: 16B-aligned rows, ~2-way banks
  __shared__ unsigned short Al[128][40];
  __shared__ unsigned short Bh[128][40];
  __shared__ unsigned short Bl[128][40];
  __shared__ int   cidxl[128];
  __shared__ float wl[128];

  const int tid = threadIdx.x;
  const int m0 = blockIdx.y * 128;
  const int n0 = blockIdx.x * 128;

  if (MODE == 1){
    int count = params[21];
    if (m0 >= count) return;
    if (tid < 128){
      int g = m0 + tid;
      if (g < count){ cidxl[tid] = cidx[g]; wl[tid] = wgt[g]; }
      else          { cidxl[tid] = 0;       wl[tid] = 0.f;   }
    }
    __syncthreads();
  }

  const int lane = tid & 63;
  const int wv   = tid >> 6;
  const int wm   = (wv & 1) << 6;
  const int wn   = (wv >> 1) << 6;
  const int lr   = lane & 15;
  const int quad = lane >> 4;
  const int kb8  = quad << 3;

  floatx4 acc[4][4];
  #pragma unroll
  for (int i = 0; i < 4; i++)
    #pragma unroll
    for (int j = 0; j < 4; j++)
      acc[i][j] = (floatx4){0.f, 0.f, 0.f, 0.f};

  const int nkb = K >> 5;
  for (int kb = 0; kb < nkb; ++kb){
    const int k0 = kb << 5;
    // stage A: fp32 -> hi/lo bf16 by truncation (residual exact)
    #pragma unroll
    for (int i = 0; i < 4; i++){
      int lin = i * 256 + tid;
      int row = lin >> 3;
      int kq  = (lin & 7) << 2;
      size_t arow = (MODE == 0) ? (size_t)(m0 + row) : (size_t)cidxl[row];
      const float4 v = *(const float4*)(A + arow * K + k0 + kq);
      unsigned int ux = __float_as_uint(v.x), uy = __float_as_uint(v.y);
      unsigned int uz = __float_as_uint(v.z), uw = __float_as_uint(v.w);
      float rx = v.x - __uint_as_float(ux & 0xFFFF0000u);
      float ry = v.y - __uint_as_float(uy & 0xFFFF0000u);
      float rz = v.z - __uint_as_float(uz & 0xFFFF0000u);
      float rw = v.w - __uint_as_float(uw & 0xFFFF0000u);
      ushort4 h, l;
      h.x = (unsigned short)(ux >> 16); l.x = (unsigned short)(__float_as_uint(rx) >> 16);
      h.y = (unsigned short)(uy >> 16); l.y = (unsigned short)(__float_as_uint(ry) >> 16);
      h.z = (unsigned short)(uz >> 16); l.z = (unsigned short)(__float_as_uint(rz) >> 16);
      h.w = (unsigned short)(uw >> 16); l.w = (unsigned short)(__float_as_uint(rw) >> 16);
      *(ushort4*)&Ah[row][kq] = h;
      *(ushort4*)&Al[row][kq] = l;
    }
    // stage B (pre-split bf16, [n][k] layout)
    #pragma unroll
    for (int i = 0; i < 2; i++){
      int lin = i * 256 + tid;
      int row = lin >> 2;
      int kq  = (lin & 3) << 3;
      size_t off = (size_t)(n0 + row) * K + k0 + kq;
      *(ushortx8*)&Bh[row][kq] = *(const ushortx8*)(Bhg + off);
      *(ushortx8*)&Bl[row][kq] = *(const ushortx8*)(Blg + off);
    }
    __syncthreads();
    shortx8 a0[4], a1[4], b0[4], b1[4];
    #pragma unroll
    for (int i = 0; i < 4; i++){
      a0[i] = *(const shortx8*)&Ah[wm + i * 16 + lr][kb8];
      a1[i] = *(const shortx8*)&Al[wm + i * 16 + lr][kb8];
      b0[i] = *(const shortx8*)&Bh[wn + i * 16 + lr][kb8];
      b1[i] = *(const shortx8*)&Bl[wn + i * 16 + lr][kb8];
    }
    #pragma unroll
    for (int i = 0; i < 4; i++){
      #pragma unroll
      for (int j = 0; j < 4; j++){
        acc[i][j] = __builtin_amdgcn_mfma_f32_16x16x32_bf16(a0[i], b0[j], acc[i][j], 0, 0, 0);
        acc[i][j] = __builtin_amdgcn_mfma_f32_16x16x32_bf16(a1[i], b0[j], acc[i][j], 0, 0, 0);
        acc[i][j] = __builtin_amdgcn_mfma_f32_16x16x32_bf16(a0[i], b1[j], acc[i][j], 0, 0, 0);
      }
    }
    __syncthreads();
  }

  // epilogue: tanh, optional store / weighting, column sums -> global atomics
  float csum[4] = {0.f, 0.f, 0.f, 0.f};
  #pragma unroll
  for (int i = 0; i < 4; i++){
    float w0 = 1.f, w1 = 1.f, w2 = 1.f, w3 = 1.f;
    if (MODE == 1){
      const float4 wv4 = *(const float4*)&wl[wm + i * 16 + (quad << 2)];
      w0 = wv4.x; w1 = wv4.y; w2 = wv4.z; w3 = wv4.w;
    }
    #pragma unroll
    for (int j = 0; j < 4; j++){
      float t0 = ftanh(acc[i][j][0]);
      float t1 = ftanh(acc[i][j][1]);
      float t2 = ftanh(acc[i][j][2]);
      float t3 = ftanh(acc[i][j][3]);
      if (MODE == 0){
        size_t base = (size_t)(m0 + wm + i * 16 + (quad << 2)) * PDIM + (n0 + wn + j * 16 + lr);
        Cout[base]            = t0;
        Cout[base +     PDIM] = t1;
        Cout[base + 2 * PDIM] = t2;
        Cout[base + 3 * PDIM] = t3;
        csum[j] += t0 + t1 + t2 + t3;
      } else {
        csum[j] += t0 * w0 + t1 * w1 + t2 * w2 + t3 * w3;
      }
    }
  }
  #pragma unroll
  for (int j = 0; j < 4; j++){
    float s = csum[j];
    s += __shfl_xor(s, 16);
    s += __shfl_xor(s, 32);
    if (lane < 16) atomicAdd(&colacc[n0 + wn + j * 16 + lane], s);
  }
}

// ---------------------------------------------------------------------------
// gates: per-token 3 gate GEMVs (fp32), router_logits out, w_top0 key, masks,
// per-expert counts, 4096-bin level-1 histograms (mantissa bits [22:11]).
// ---------------------------------------------------------------------------
__global__ void gates_kernel(const float* __restrict__ patches,
                             const float* __restrict__ Wg0,
                             const float* __restrict__ Wg1,
                             const float* __restrict__ Wg2,
                             float* __restrict__ dout,
                             unsigned int* __restrict__ wkey,
                             unsigned char* __restrict__ mask3,
                             int* __restrict__ params,
                             int* __restrict__ hist)
{
  __shared__ int lc[3];
  const int tid = threadIdx.x;
  if (tid < 3) lc[tid] = 0;
  __syncthreads();
  const int lane = tid & 63;
  float wg[3][16];
  const float* Wgp[3] = {Wg0, Wg1, Wg2};
  #pragma unroll
  for (int g = 0; g < 3; g++){
    #pragma unroll
    for (int j = 0; j < 4; j++){
      float4 v = *(const float4*)(Wgp[g] + lane * 16 + j * 4);
      wg[g][j * 4 + 0] = v.x; wg[g][j * 4 + 1] = v.y;
      wg[g][j * 4 + 2] = v.z; wg[g][j * 4 + 3] = v.w;
    }
  }
  const int nw = gridDim.x << 2;
  for (int t = blockIdx.x * 4 + (tid >> 6); t < T_TOK; t += nw){
    const float* row = patches + (size_t)t * PDIM + lane * 8;
    float4 v0 = *(const float4*)row;
    float4 v1 = *(const float4*)(row + 4);
    float x[8] = {v0.x, v0.y, v0.z, v0.w, v1.x, v1.y, v1.z, v1.w};
    float g00 = 0, g01 = 0, g10 = 0, g11 = 0, g20 = 0, g21 = 0;
    #pragma unroll
    for (int j = 0; j < 8; j++){
      g00 += x[j] * wg[0][2 * j]; g01 += x[j] * wg[0][2 * j + 1];
      g10 += x[j] * wg[1][2 * j]; g11 += x[j] * wg[1][2 * j + 1];
      g20 += x[j] * wg[2][2 * j]; g21 += x[j] * wg[2][2 * j + 1];
    }
    #pragma unroll
    for (int off = 1; off < 64; off <<= 1){
      g00 += __shfl_xor(g00, off); g01 += __shfl_xor(g01, off);
      g10 += __shfl_xor(g10, off); g11 += __shfl_xor(g11, off);
      g20 += __shfl_xor(g20, off); g21 += __shfl_xor(g21, off);
    }
    if (lane == 0){
      dout[8 + 2 * t]     = g00;
      dout[8 + 2 * t + 1] = g01;
      int m0 = g01 > g00;
      int m1 = g11 > g10;
      int m2 = g21 > g20;
      mask3[t] = (unsigned char)(m0 | (m1 << 1) | (m2 << 2));
      float d = fabsf(g00 - g01);
      float w = 1.0f / (1.0f + __expf(-d));   // top-1 softmax prob in [0.5,1)
      unsigned int u = __float_as_uint(w);
      u = u < 0x3F000000u ? 0x3F000000u : u;
      u = u > 0x3F7FFFFFu ? 0x3F7FFFFFu : u;
      wkey[t] = u;
      int b = (int)((u >> 11) & 0xFFFu);      // mantissa bits [22:11]
      if (m0){ atomicAdd(&hist[b], 1);         atomicAdd(&lc[0], 1); }
      if (m1){ atomicAdd(&hist[4096 + b], 1);  atomicAdd(&lc[1], 1); }
      if (m2){ atomicAdd(&hist[8192 + b], 1);  atomicAdd(&lc[2], 1); }
    }
  }
  __syncthreads();
  if (tid < 3 && lc[tid]) atomicAdd(&params[tid], lc[tid]);
}

// ---------------------------------------------------------------------------
// find_bucket: nums = floor(cnt*frac) via shifts; locate 12-bit bucket of
// the nums-th largest key (suffix scan over 4096 bins).
// params: [0..2] cnt [3..5] nums [6..8] bucket [9..11] rank-in-bucket
//         [12..14] theta_u [15..17] r_ties [18..20] c_eq [21] compact count
// ---------------------------------------------------------------------------
__global__ void find_bucket(int* __restrict__ params, const int* __restrict__ hist)
{
  __shared__ int cs[256], orig[256];
  __shared__ int selc, selrk;
  const int tid = threadIdx.x;
  for (int e = 0; e < 3; e++){
    int cnt = params[e];
    int shift = (e == 1) ? 1 : 2;              // FRACS 0.25,0.5,0.25 exact
    int nums = cnt >> shift;
    if (nums == 0) nums = cnt;
    if (tid == 0) params[3 + e] = nums;
    __syncthreads();
    if (nums == 0){
      if (tid == 0){ params[6 + e] = -1; params[9 + e] = 0; }
      __syncthreads();
      continue;
    }
    const int* h = hist + e * 4096 + tid * 16;
    int s = 0;
    #pragma unroll
    for (int j = 0; j < 16; j++) s += h[j];
    cs[tid] = s; orig[tid] = s;
    __syncthreads();
    for (int off = 1; off < 256; off <<= 1){
      int v = (tid + off < 256) ? cs[tid + off] : 0;
      __syncthreads();
      cs[tid] += v;
      __syncthreads();
    }
    if (cs[tid] >= nums && (cs[tid] - orig[tid]) < nums){
      selc = tid; selrk = nums - (cs[tid] - orig[tid]);
    }
    __syncthreads();
    if (tid == 0){
      int ch = selc, rk = selrk;
      const int* hh = hist + e * 4096 + ch * 16;
      int acc = 0;
      for (int j = 15; j >= 0; j--){
        int c = hh[j];
        if (acc + c >= rk){ params[6 + e] = ch * 16 + j; params[9 + e] = rk - acc; break; }
        acc += c;
      }
    }
    __syncthreads();
  }
}

// ---------------------------------------------------------------------------
// level2hist: 2048-bin histogram (mantissa bits [10:0]) of keys within the
// chosen bucket. grid (32,3), global atomics.
// ---------------------------------------------------------------------------
__global__ void level2hist(const int* __restrict__ params, const unsigned int* __restrict__ wkey,
                           const unsigned char* __restrict__ mask3, int* __restrict__ h2)
{
  const int e = blockIdx.y;
  const int B = params[6 + e];
  if (B < 0) return;
  const unsigned char bit = (unsigned char)(1u << e);
  const int t0 = blockIdx.x * 2048 + threadIdx.x;
  #pragma unroll
  for (int i = 0; i < 8; i++){
    int t = t0 + i * 256;
    if (mask3[t] & bit){
      unsigned int u = wkey[t];
      if ((int)((u >> 11) & 0xFFFu) == B) atomicAdd(&h2[e * 2048 + (u & 2047u)], 1);
    }
  }
}

// ---------------------------------------------------------------------------
// find_theta: exact threshold key (bucket + sub-bin = all 23 mantissa bits),
// ties-to-take r, tie count c_eq. grid = 3 blocks.
// ---------------------------------------------------------------------------
__global__ void find_theta(int* __restrict__ params, const int* __restrict__ h2)
{
  const int e = blockIdx.x;
  const int tid = threadIdx.x;
  __shared__ int cs[256], orig[256];
  __shared__ int selc;
  int B = params[6 + e], rank = params[9 + e];
  if (B < 0){
    if (tid == 0){ params[12 + e] = (int)0xFFFFFFFFu; params[15 + e] = 0; params[18 + e] = 0; }
    return;
  }
  const int* h = h2 + e * 2048 + tid * 8;
  int s = 0;
  #pragma unroll
  for (int j = 0; j < 8; j++) s += h[j];
  cs[tid] = s; orig[tid] = s;
  __syncthreads();
  for (int off = 1; off < 256; off <<= 1){
    int v = (tid + off < 256) ? cs[tid + off] : 0;
    __syncthreads();
    cs[tid] += v;
    __syncthreads();
  }
  if (cs[tid] >= rank && (cs[tid] - orig[tid]) < rank) selc = tid;
  __syncthreads();
  if (tid == 0){
    int ch = selc;
    int rk = rank - (cs[ch] - orig[ch]);
    const int* hh = h2 + e * 2048 + ch * 8;
    int acc = 0;
    for (int j = 7; j >= 0; j--){
      int c = hh[j];
      if (acc + c >= rk){
        int sub = ch * 8 + j;
        params[12 + e] = (int)(0x3F000000u | ((unsigned)B << 11) | (unsigned)sub);
        params[15 + e] = rk - acc;
        params[18 + e] = c;
        break;
      }
      acc += c;
    }
  }
}

// ---------------------------------------------------------------------------
// mark_sel: sel = mask & (key>theta || (key==theta && tie-rank<r)).
// Fast path when all ties taken; slow stable index-ordered path otherwise.
// ---------------------------------------------------------------------------
__global__ void mark_sel(const int* __restrict__ params, const unsigned int* __restrict__ wkey,
                         const unsigned char* __restrict__ mask3, unsigned char* __restrict__ selb)
{
  const int e = blockIdx.y;
  const int bx = blockIdx.x;
  const int tid = threadIdx.x;
  const unsigned int theta = (unsigned int)params[12 + e];
  const int r = params[15 + e];
  const int ceq = params[18 + e];
  const unsigned char bit = (unsigned char)(1u << e);
  unsigned char* sb = selb + e * T_TOK;
  if (ceq == r){
    int t0 = bx * 2048;
    #pragma unroll
    for (int i = 0; i < 8; i++){
      int t = t0 + i * 256 + tid;
      unsigned char mk = mask3[t] & bit;
      sb[t] = (mk && wkey[t] >= theta) ? 1 : 0;
    }
  } else {
    if (bx) return;
    __shared__ int basec;
    __shared__ int wsum[4];
    if (tid == 0) basec = 0;
    __syncthreads();
    const int lane = tid & 63, w = tid >> 6;
    for (int c = 0; c < 256; c++){
      int t = c * 256 + tid;
      unsigned char mk = mask3[t] & bit;
      unsigned int u = mk ? wkey[t] : 0u;
      bool gt = mk && (u > theta);
      bool eq = mk && (u == theta);
      unsigned long long bal = __ballot(eq);
      if (lane == 0) wsum[w] = __popcll(bal);
      __syncthreads();
      int wbase = 0;
      for (int ww = 0; ww < w; ww++) wbase += wsum[ww];
      int pos = basec + wbase + __popcll(bal & ((1ull << lane) - 1ull));
      sb[t] = (gt || (eq && pos < r)) ? 1 : 0;
      __syncthreads();
      if (tid == 0) basec += wsum[0] + wsum[1] + wsum[2] + wsum[3];
      __syncthreads();
    }
  }
}

// ---------------------------------------------------------------------------
// compact: list of tokens with total_sel>0 (order irrelevant for the sums),
// with float multiplicity weight. Count in params[21].
// ---------------------------------------------------------------------------
__global__ void compact(const unsigned char* __restrict__ selb, int* __restrict__ cidx,
                        float* __restrict__ wgt, int* __restrict__ params)
{
  int t = blockIdx.x * 256 + threadIdx.x;
  int ts = selb[t] + selb[T_TOK + t] + selb[2 * T_TOK + t];
  int lane = threadIdx.x & 63;
  unsigned long long bal = __ballot(ts > 0);
  int base = 0;
  if (lane == 0) base = atomicAdd(&params[21], __popcll(bal));
  base = __shfl(base, 0);
  if (ts){
    int pos = base + __popcll(bal & ((1ull << lane) - 1ull));
    cidx[pos] = t;
    wgt[pos] = (float)ts;
  }
}

// ---------------------------------------------------------------------------
// meanfeat_c: column sums of patches over sel0 / sel1 rows (experts 0,1 only;
// expert 2's mean_feat is unused). Runs over the compacted union list.
// ---------------------------------------------------------------------------
__global__ void meanfeat_c(const float* __restrict__ patches, const unsigned char* __restrict__ selb,
                           const int* __restrict__ cidx, const int* __restrict__ params,
                           float* __restrict__ mf)
{
  const int count = params[21];
  const int base = blockIdx.x * 256;
  if (base >= count) return;
  const int n = min(256, count - base);
  const int tid = threadIdx.x;
  __shared__ int cl[256];
  __shared__ unsigned char f0s[256], f1s[256];
  if (tid < n){
    int c = cidx[base + tid];
    cl[tid] = c;
    f0s[tid] = selb[c];
    f1s[tid] = selb[T_TOK + c];
  }
  __syncthreads();
  float s00 = 0, s01 = 0, s10 = 0, s11 = 0;
  for (int i = 0; i < n; i++){
    int f0 = f0s[i], f1 = f1s[i];
    if (f0 | f1){
      float2 v = *(const float2*)(patches + (size_t)cl[i] * PDIM + tid * 2);
      if (f0){ s00 += v.x; s01 += v.y; }
      if (f1){ s10 += v.x; s11 += v.y; }
    }
  }
  atomicAdd(&mf[tid * 2],       s00);
  atomicAdd(&mf[tid * 2 + 1],   s01);
  atomicAdd(&mf[512 + tid * 2],     s10);
  atomicAdd(&mf[512 + tid * 2 + 1], s11);
}

// ---------------------------------------------------------------------------
// finalize: all small outputs.
// d_out: [0,2) e_Y_logits | [2] e_Y_hat | [3,5) Y_logits | [5,7) Y_prob |
//        [7] Y_hat | [8,131080) router_logits | [131080] joint | [131081,85) distribute
// ---------------------------------------------------------------------------
__global__ void finalize(const float* __restrict__ bagsum, const float* __restrict__ aggsum,
                         const float* __restrict__ mf, const int* __restrict__ params,
                         const float* __restrict__ Wcls1, const float* __restrict__ Wclf,
                         const float* __restrict__ Wacls, float* __restrict__ dout)
{
  const int lane = threadIdx.x;  // 64 threads
  const int nums0 = params[3], nums1 = params[4], nums2 = params[5];
  const float invT = 1.0f / 65536.0f;
  const float inv0 = 1.0f / (float)(nums0 > 0 ? nums0 : 1);
  const float inv1 = 1.0f / (float)(nums1 > 0 ? nums1 : 1);
  const float totn = (float)(nums0 + nums1 + nums2);
  const float invA = 1.0f / fmaxf(totn, 1.0f);
  float y0 = 0, y1 = 0, a0 = 0, a1 = 0;
  float l00 = 0, l01 = 0, l02 = 0, l10 = 0, l11 = 0, l12 = 0;
  #pragma unroll
  for (int j = 0; j < 8; j++){
    int p = lane * 8 + j;
    float bg = bagsum[p] * invT;
    y0 += bg * Wcls1[p * 2]; y1 += bg * Wcls1[p * 2 + 1];
    float ag = aggsum[p] * invA;
    a0 += ag * Wacls[p * 2]; a1 += ag * Wacls[p * 2 + 1];
    float m0v = mf[p] * inv0;
    l00 += m0v * Wclf[p * 3]; l01 += m0v * Wclf[p * 3 + 1]; l02 += m0v * Wclf[p * 3 + 2];
    float m1v = mf[512 + p] * inv1;
    l10 += m1v * Wclf[1536 + p * 3]; l11 += m1v * Wclf[1536 + p * 3 + 1]; l12 += m1v * Wclf[1536 + p * 3 + 2];
  }
  #pragma unroll
  for (int off = 1; off < 64; off <<= 1){
    y0 += __shfl_xor(y0, off);   y1 += __shfl_xor(y1, off);
    a0 += __shfl_xor(a0, off);   a1 += __shfl_xor(a1, off);
    l00 += __shfl_xor(l00, off); l01 += __shfl_xor(l01, off); l02 += __shfl_xor(l02, off);
    l10 += __shfl_xor(l10, off); l11 += __shfl_xor(l11, off); l12 += __shfl_xor(l12, off);
  }
  if (lane == 0){
    dout[0] = a0; dout[1] = a1;
    dout[2] = (a1 > a0) ? 1.0f : 0.0f;
    dout[3] = y0; dout[4] = y1;
    float mx = fmaxf(y0, y1), e0 = expf(y0 - mx), e1 = expf(y1 - mx), inv = 1.0f / (e0 + e1);
    dout[5] = e0 * inv; dout[6] = e1 * inv;
    dout[7] = (y1 > y0) ? 1.0f : 0.0f;
    float m3 = fmaxf(fmaxf(l00, l01), l02);
    float lse0 = m3 + logf(expf(l00 - m3) + expf(l01 - m3) + expf(l02 - m3));
    float m4 = fmaxf(fmaxf(l10, l11), l12);
    float lse1 = m4 + logf(expf(l10 - m4) + expf(l11 - m4) + expf(l12 - m4));
    dout[131080] = (lse0 - l00) + (lse1 - l11);
    dout[131081] = 65536.0f;
    dout[131082] = (float)nums0;
    dout[131083] = (float)nums1;
    dout[131084] = (float)nums2;
  }
}

// ---------------------------------------------------------------------------
extern "C" void kernel_launch(void* const* d_in, const int* in_sizes, int n_in,
                              void* d_out, int out_size, void* d_ws, size_t ws_size,
                              hipStream_t stream)
{
  const float* X      = (const float*)d_in[0];
  const float* W_t1   = (const float*)d_in[1];
  const float* W_cls1 = (const float*)d_in[2];
  const float* Wg0    = (const float*)d_in[3];
  const float* Wg1    = (const float*)d_in[4];
  const float* Wg2    = (const float*)d_in[5];
  const float* W_clf  = (const float*)d_in[6];
  const float* W_a1   = (const float*)d_in[7];
  const float* W_acls = (const float*)d_in[8];
  float* dout = (float*)d_out;
  char* ws = (char*)d_ws;

  // workspace layout (bytes)
  float*          patches = (float*)         (ws + 0);            // 134217728
  unsigned short* W1th    = (unsigned short*)(ws + 134217728);    // 1048576
  unsigned short* W1tl    = (unsigned short*)(ws + 135266304);    // 1048576
  unsigned short* Wath    = (unsigned short*)(ws + 136314880);    // 524288
  unsigned short* Watl    = (unsigned short*)(ws + 136839168);    // 524288
  unsigned int*   wkey    = (unsigned int*)  (ws + 137363456);    // 262144
  unsigned char*  mask3   = (unsigned char*) (ws + 137625600);    // 65536
  unsigned char*  selb    = (unsigned char*) (ws + 137691136);    // 196608
  int*            cidx    = (int*)           (ws + 137887744);    // 262144
  float*          wgt     = (float*)         (ws + 138149888);    // 262144
  int*            zbase   = (int*)           (ws + 138412032);    // zeroed region
  int*            hist    = zbase;                                // 3*4096
  int*            h2      = zbase + 12288;                        // 3*2048
  int*            params  = zbase + 18432;                        // 64
  float*          bagsum  = (float*)(zbase + 18496);              // 512
  float*          aggsum  = (float*)(zbase + 19008);              // 512
  float*          mf      = (float*)(zbase + 19520);              // 1024  (end 20544)

  prep<<<3153, 256, 0, stream>>>(W_t1, W_a1, W1th, W1tl, Wath, Watl, zbase);

  gemm_split<0><<<dim3(4, 512), 256, 0, stream>>>(
      X, W1th, W1tl, patches, bagsum, nullptr, nullptr, nullptr);

  gates_kernel<<<512, 256, 0, stream>>>(
      patches, Wg0, Wg1, Wg2, dout, wkey, mask3, params, hist);

  find_bucket<<<1, 256, 0, stream>>>(params, hist);
  level2hist<<<dim3(32, 3), 256, 0, stream>>>(params, wkey, mask3, h2);
  find_theta<<<3, 256, 0, stream>>>(params, h2);
  mark_sel<<<dim3(32, 3), 256, 0, stream>>>(params, wkey, mask3, selb);
  compact<<<256, 256, 0, stream>>>(selb, cidx, wgt, params);

  meanfeat_c<<<256, 256, 0, stream>>>(patches, selb, cidx, params, mf);

  gemm_split<1><<<dim3(4, 512), 256, 0, stream>>>(
      patches, Wath, Watl, nullptr, aggsum, cidx, wgt, params);

  finalize<<<1, 64, 0, stream>>>(bagsum, aggsum, mf, params, W_cls1, W_clf, W_acls, dout);
}